// Round 2
// baseline (866.501 us; speedup 1.0000x reference)
//
#include <hip/hip_runtime.h>
#include <hip/hip_bf16.h>

#define N_NODES 20000
#define N_EDGES 320000
#define DIM 256
#define H_HEADS 4

typedef _Float16 f16x8 __attribute__((ext_vector_type(8)));
typedef float f32x4v __attribute__((ext_vector_type(4)));

// ---------------- init: convert W to f16 transposed, zero stats ----------------
__global__ void k_init(const float* __restrict__ Wn, const float* __restrict__ We,
                       _Float16* __restrict__ WTn, _Float16* __restrict__ WTe,
                       unsigned int* __restrict__ m_enc, unsigned int* __restrict__ counts)
{
    int i = blockIdx.x * 256 + threadIdx.x;
    if (i < DIM * DIM) {
        int n = i >> 8, k = i & 255;
        WTn[i] = (_Float16)Wn[k * DIM + n];
        WTe[i] = (_Float16)We[k * DIM + n];
    }
    if (i < N_NODES * H_HEADS) m_enc[i] = 0u;
    if (i < N_NODES + 1) counts[i] = 0u;
}

// ---------------- CSR build ----------------
__global__ void k_hist(const int* __restrict__ dst, unsigned int* __restrict__ counts)
{
    int i = blockIdx.x * 256 + threadIdx.x;
    if (i < N_EDGES) atomicAdd(&counts[dst[i]], 1u);
}

// work-efficient single-block scan: 20 elems/thread serial + one 10-step LDS scan
__global__ __launch_bounds__(1024) void k_scan(unsigned int* __restrict__ counts,
                                               unsigned int* __restrict__ cursor)
{
    __shared__ unsigned int buf[1024];
    const int t = threadIdx.x;
    const int b0 = t * 20;                     // 1024*20 = 20480 >= 20000
    unsigned int v[20];
    unsigned int s = 0;
#pragma unroll
    for (int i = 0; i < 20; ++i) {
        int idx = b0 + i;
        v[i] = (idx < N_NODES) ? counts[idx] : 0u;
        s += v[i];
    }
    buf[t] = s;
    __syncthreads();
    for (int off = 1; off < 1024; off <<= 1) {
        unsigned int add = (t >= off) ? buf[t - off] : 0u;
        __syncthreads();
        buf[t] += add;
        __syncthreads();
    }
    unsigned int run = buf[t] - s;             // exclusive prefix
#pragma unroll
    for (int i = 0; i < 20; ++i) {
        int idx = b0 + i;
        if (idx < N_NODES) { counts[idx] = run; cursor[idx] = run; }
        run += v[i];
    }
    if (t == 1023) counts[N_NODES] = buf[1023];
}

__global__ void k_scatter(const int* __restrict__ dst, unsigned int* __restrict__ cursor,
                          int* __restrict__ esort)
{
    int i = blockIdx.x * 256 + threadIdx.x;
    if (i < N_EDGES) {
        unsigned int p = atomicAdd(&cursor[dst[i]], 1u);
        esort[p] = i;
    }
}

// ---------------- node projection GEMM: ft = nfeat @ W_node  (f32 out) ----------------
// Full-K LDS stage (one barrier), then 128 barrier-free MFMAs.
// Row stride 296 f16 = 37 x 16B bank-groups -> ~2-way LDS aliasing (free).
__global__ __launch_bounds__(256) void k_gemm_node(
    const float* __restrict__ A, const _Float16* __restrict__ WT,
    float* __restrict__ C, int M)
{
    __shared__ __align__(16) _Float16 Alds[64][296];
    const int t = threadIdx.x;
    const int m0 = blockIdx.x * 64;
    const int lane = t & 63, w = t >> 6;
    const int q = lane >> 4, c16 = lane & 15;
    const int srow = t >> 2;
    const int scol0 = (t & 3) * 64;
    const float* gp = A + (size_t)(m0 + srow) * DIM + scol0;
    const bool rowok = (m0 + srow) < M;
#pragma unroll
    for (int i = 0; i < 8; ++i) {
        f16x8 h8;
        if (rowok) {
            float4 v0 = *(const float4*)(gp + i * 8);
            float4 v1 = *(const float4*)(gp + i * 8 + 4);
            h8[0]=(_Float16)v0.x; h8[1]=(_Float16)v0.y; h8[2]=(_Float16)v0.z; h8[3]=(_Float16)v0.w;
            h8[4]=(_Float16)v1.x; h8[5]=(_Float16)v1.y; h8[6]=(_Float16)v1.z; h8[7]=(_Float16)v1.w;
        } else {
            h8 = (f16x8)(_Float16)0.f;
        }
        *(f16x8*)&Alds[srow][scol0 + i * 8] = h8;
    }
    __syncthreads();

    f32x4v acc[4][4] = {};
#pragma unroll
    for (int k0 = 0; k0 < DIM; k0 += 32) {
        f16x8 bfr[4], afr[4];
#pragma unroll
        for (int ni = 0; ni < 4; ++ni) {
            int col = (w << 6) + (ni << 4) + c16;
            bfr[ni] = *(const f16x8*)(WT + (size_t)col * DIM + k0 + q * 8);
        }
#pragma unroll
        for (int mi = 0; mi < 4; ++mi)
            afr[mi] = *(const f16x8*)&Alds[c16 + 16 * mi][k0 + q * 8];
#pragma unroll
        for (int mi = 0; mi < 4; ++mi)
#pragma unroll
            for (int ni = 0; ni < 4; ++ni)
                acc[mi][ni] = __builtin_amdgcn_mfma_f32_16x16x32_f16(afr[mi], bfr[ni], acc[mi][ni], 0, 0, 0);
    }

#pragma unroll
    for (int mi = 0; mi < 4; ++mi) {
#pragma unroll
        for (int reg = 0; reg < 4; ++reg) {
            int row = m0 + 16 * mi + 4 * q + reg;
            if (row < M) {
#pragma unroll
                for (int ni = 0; ni < 4; ++ni) {
                    int c = (w << 6) + (ni << 4) + c16;
                    C[(size_t)row * DIM + c] = acc[mi][ni][reg];
                }
            }
        }
    }
}

// ---------------- fused edge GEMM: eft, ft_prime (f16), a, segment-max ----------------
__global__ __launch_bounds__(256) void k_gemm_edge(
    const float* __restrict__ efeat, const _Float16* __restrict__ WT,
    const float* __restrict__ ft, const int* __restrict__ src, const int* __restrict__ dst,
    _Float16* __restrict__ ftp, float* __restrict__ a_ws, unsigned int* __restrict__ m_enc)
{
    __shared__ __align__(16) _Float16 Alds[64][296];
    const int t = threadIdx.x;
    const int e0 = blockIdx.x * 64;
    const int lane = t & 63, w = t >> 6;
    const int q = lane >> 4, c16 = lane & 15;
    const int srow = t >> 2;
    const int scol0 = (t & 3) * 64;
    const float* gp = efeat + (size_t)(e0 + srow) * DIM + scol0;
#pragma unroll
    for (int i = 0; i < 8; ++i) {
        float4 v0 = *(const float4*)(gp + i * 8);
        float4 v1 = *(const float4*)(gp + i * 8 + 4);
        f16x8 h8;
        h8[0]=(_Float16)v0.x; h8[1]=(_Float16)v0.y; h8[2]=(_Float16)v0.z; h8[3]=(_Float16)v0.w;
        h8[4]=(_Float16)v1.x; h8[5]=(_Float16)v1.y; h8[6]=(_Float16)v1.z; h8[7]=(_Float16)v1.w;
        *(f16x8*)&Alds[srow][scol0 + i * 8] = h8;
    }
    __syncthreads();

    f32x4v acc[4][4] = {};
#pragma unroll
    for (int k0 = 0; k0 < DIM; k0 += 32) {
        f16x8 bfr[4], afr[4];
#pragma unroll
        for (int ni = 0; ni < 4; ++ni) {
            int col = (w << 6) + (ni << 4) + c16;
            bfr[ni] = *(const f16x8*)(WT + (size_t)col * DIM + k0 + q * 8);
        }
#pragma unroll
        for (int mi = 0; mi < 4; ++mi)
            afr[mi] = *(const f16x8*)&Alds[c16 + 16 * mi][k0 + q * 8];
#pragma unroll
        for (int mi = 0; mi < 4; ++mi)
#pragma unroll
            for (int ni = 0; ni < 4; ++ni)
                acc[mi][ni] = __builtin_amdgcn_mfma_f32_16x16x32_f16(afr[mi], bfr[ni], acc[mi][ni], 0, 0, 0);
    }

    // epilogue: ft_prime = eft + ft[src]; a = dot(ft_prime, ft[dst]) per head
#pragma unroll
    for (int mi = 0; mi < 4; ++mi) {
#pragma unroll
        for (int reg = 0; reg < 4; ++reg) {
            int r = 16 * mi + 4 * q + reg;
            int e = e0 + r;
            int se = src[e], de = dst[e];
            float dotp = 0.f;
#pragma unroll
            for (int ni = 0; ni < 4; ++ni) {
                int c = (w << 6) + (ni << 4) + c16;
                float v = acc[mi][ni][reg] + ft[(size_t)se * DIM + c];
                ftp[(size_t)e * DIM + c] = (_Float16)v;
                dotp += v * ft[(size_t)de * DIM + c];
            }
            dotp += __shfl_xor(dotp, 1);
            dotp += __shfl_xor(dotp, 2);
            dotp += __shfl_xor(dotp, 4);
            dotp += __shfl_xor(dotp, 8);
            if (c16 == 0) {
                a_ws[e * H_HEADS + w] = dotp;
                unsigned int u = __float_as_uint(dotp);
                u = (u & 0x80000000u) ? ~u : (u | 0x80000000u);
                atomicMax(&m_enc[de * H_HEADS + w], u);
            }
        }
    }
}

// ---------------- CSR aggregation with fused softmax ----------------
__device__ __forceinline__ float dec_max(unsigned int u)
{
    return (u & 0x80000000u) ? __uint_as_float(u & 0x7fffffffu) : __uint_as_float(~u);
}

__global__ __launch_bounds__(256) void k_agg(
    const unsigned int* __restrict__ offs, const int* __restrict__ esort,
    const float* __restrict__ a_ws, const unsigned int* __restrict__ m_enc,
    const _Float16* __restrict__ ftp, float* __restrict__ out)
{
    int n = blockIdx.x;
    int c = threadIdx.x;
    int h = c >> 6;
    int beg = (int)offs[n], end = (int)offs[n + 1];
    float m = dec_max(m_enc[n * H_HEADS + h]);
    // pass 1: softmax denominator (redundant across the 64 threads of a head)
    float s = 0.f;
    for (int j = beg; j < end; ++j) {
        int e = esort[j];
        s += __expf(a_ws[e * H_HEADS + h] - m);
    }
    float inv = (end > beg) ? 0.125f / s : 0.f;   // 1/sqrt(F) = 1/8
    // pass 2: weighted aggregation
    float acc = 0.f;
    for (int j = beg; j < end; ++j) {
        int e = esort[j];
        float wgt = __expf(a_ws[e * H_HEADS + h] - m) * inv;
        acc += wgt * (float)ftp[(size_t)e * DIM + c];
    }
    out[(size_t)n * DIM + c] = acc;
}

// ---------------- launch ----------------
extern "C" void kernel_launch(void* const* d_in, const int* in_sizes, int n_in,
                              void* d_out, int out_size, void* d_ws, size_t ws_size,
                              hipStream_t stream)
{
    const float* nfeat = (const float*)d_in[0];
    const float* efeat = (const float*)d_in[1];
    const int* src = (const int*)d_in[2];
    const int* dst = (const int*)d_in[3];
    const float* Wn = (const float*)d_in[4];
    const float* We = (const float*)d_in[5];
    float* out = (float*)d_out;

    char* ws = (char*)d_ws;
    size_t off = 0;
    auto alloc = [&](size_t bytes) -> void* {
        off = (off + 255) & ~(size_t)255;
        void* p = ws + off;
        off += bytes;
        return p;
    };

    _Float16* WTn = (_Float16*)alloc((size_t)DIM * DIM * 2);
    _Float16* WTe = (_Float16*)alloc((size_t)DIM * DIM * 2);
    float* ft = (float*)alloc((size_t)N_NODES * DIM * 4);
    _Float16* ftp = (_Float16*)alloc((size_t)N_EDGES * DIM * 2);
    float* a_ws = (float*)alloc((size_t)N_EDGES * H_HEADS * 4);
    unsigned int* m_enc = (unsigned int*)alloc((size_t)N_NODES * H_HEADS * 4);
    unsigned int* counts = (unsigned int*)alloc((size_t)(N_NODES + 1) * 4);
    unsigned int* cursor = (unsigned int*)alloc((size_t)N_NODES * 4);
    int* esort = (int*)alloc((size_t)N_EDGES * 4);

    k_init<<<320, 256, 0, stream>>>(Wn, We, WTn, WTe, m_enc, counts);
    k_hist<<<(N_EDGES + 255) / 256, 256, 0, stream>>>(dst, counts);
    k_scan<<<1, 1024, 0, stream>>>(counts, cursor);
    k_scatter<<<(N_EDGES + 255) / 256, 256, 0, stream>>>(dst, cursor, esort);
    k_gemm_node<<<(N_NODES + 63) / 64, 256, 0, stream>>>(nfeat, WTn, ft, N_NODES);
    k_gemm_edge<<<N_EDGES / 64, 256, 0, stream>>>(efeat, WTe, ft, src, dst, ftp, a_ws, m_enc);
    k_agg<<<N_NODES, 256, 0, stream>>>(counts, esort, a_ws, m_enc, ftp, out);
}

// Round 3
// 848.187 us; speedup vs baseline: 1.0216x; 1.0216x over previous
//
#include <hip/hip_runtime.h>
#include <hip/hip_bf16.h>

#define N_NODES 20000
#define N_EDGES 320000
#define DIM 256
#define H_HEADS 4
#define AGG_CH 128

typedef _Float16 f16x8 __attribute__((ext_vector_type(8)));
typedef float f32x4v __attribute__((ext_vector_type(4)));

// ---------------- init: convert W to f16 transposed, zero stats ----------------
__global__ void k_init(const float* __restrict__ Wn, const float* __restrict__ We,
                       _Float16* __restrict__ WTn, _Float16* __restrict__ WTe,
                       unsigned int* __restrict__ m_enc, unsigned int* __restrict__ counts)
{
    int i = blockIdx.x * 256 + threadIdx.x;
    if (i < DIM * DIM) {
        int n = i >> 8, k = i & 255;
        WTn[i] = (_Float16)Wn[k * DIM + n];
        WTe[i] = (_Float16)We[k * DIM + n];
    }
    if (i < N_NODES * H_HEADS) m_enc[i] = 0u;
    if (i < N_NODES + 1) counts[i] = 0u;
}

// ---------------- CSR build ----------------
__global__ void k_hist(const int* __restrict__ dst, unsigned int* __restrict__ counts)
{
    int i = blockIdx.x * 256 + threadIdx.x;
    if (i < N_EDGES) atomicAdd(&counts[dst[i]], 1u);
}

__global__ __launch_bounds__(1024) void k_scan(unsigned int* __restrict__ counts,
                                               unsigned int* __restrict__ cursor)
{
    __shared__ unsigned int buf[1024];
    const int t = threadIdx.x;
    const int b0 = t * 20;
    unsigned int v[20];
    unsigned int s = 0;
#pragma unroll
    for (int i = 0; i < 20; ++i) {
        int idx = b0 + i;
        v[i] = (idx < N_NODES) ? counts[idx] : 0u;
        s += v[i];
    }
    buf[t] = s;
    __syncthreads();
    for (int off = 1; off < 1024; off <<= 1) {
        unsigned int add = (t >= off) ? buf[t - off] : 0u;
        __syncthreads();
        buf[t] += add;
        __syncthreads();
    }
    unsigned int run = buf[t] - s;
#pragma unroll
    for (int i = 0; i < 20; ++i) {
        int idx = b0 + i;
        if (idx < N_NODES) { counts[idx] = run; cursor[idx] = run; }
        run += v[i];
    }
    if (t == 1023) counts[N_NODES] = buf[1023];
}

__global__ void k_scatter(const int* __restrict__ dst, unsigned int* __restrict__ cursor,
                          int* __restrict__ esort)
{
    int i = blockIdx.x * 256 + threadIdx.x;
    if (i < N_EDGES) {
        unsigned int p = atomicAdd(&cursor[dst[i]], 1u);
        esort[p] = i;
    }
}

// ---------------- node projection GEMM: ft = nfeat @ W_node  (f32 + f16 out) ----------------
__global__ __launch_bounds__(256) void k_gemm_node(
    const float* __restrict__ A, const _Float16* __restrict__ WT,
    float* __restrict__ C32, _Float16* __restrict__ C16, int M)
{
    __shared__ __align__(16) _Float16 Alds[64][296];
    const int t = threadIdx.x;
    const int m0 = blockIdx.x * 64;
    const int lane = t & 63, w = t >> 6;
    const int q = lane >> 4, c16 = lane & 15;
    const int srow = t >> 2;
    const int scol0 = (t & 3) * 64;
    const float* gp = A + (size_t)(m0 + srow) * DIM + scol0;
    const bool rowok = (m0 + srow) < M;
#pragma unroll
    for (int i = 0; i < 8; ++i) {
        f16x8 h8;
        if (rowok) {
            float4 v0 = *(const float4*)(gp + i * 8);
            float4 v1 = *(const float4*)(gp + i * 8 + 4);
            h8[0]=(_Float16)v0.x; h8[1]=(_Float16)v0.y; h8[2]=(_Float16)v0.z; h8[3]=(_Float16)v0.w;
            h8[4]=(_Float16)v1.x; h8[5]=(_Float16)v1.y; h8[6]=(_Float16)v1.z; h8[7]=(_Float16)v1.w;
        } else {
            h8 = (f16x8)(_Float16)0.f;
        }
        *(f16x8*)&Alds[srow][scol0 + i * 8] = h8;
    }
    __syncthreads();

    f32x4v acc[4][4] = {};
#pragma unroll
    for (int k0 = 0; k0 < DIM; k0 += 32) {
        f16x8 bfr[4], afr[4];
#pragma unroll
        for (int ni = 0; ni < 4; ++ni) {
            int col = (w << 6) + (ni << 4) + c16;
            bfr[ni] = *(const f16x8*)(WT + (size_t)col * DIM + k0 + q * 8);
        }
#pragma unroll
        for (int mi = 0; mi < 4; ++mi)
            afr[mi] = *(const f16x8*)&Alds[c16 + 16 * mi][k0 + q * 8];
#pragma unroll
        for (int mi = 0; mi < 4; ++mi)
#pragma unroll
            for (int ni = 0; ni < 4; ++ni)
                acc[mi][ni] = __builtin_amdgcn_mfma_f32_16x16x32_f16(afr[mi], bfr[ni], acc[mi][ni], 0, 0, 0);
    }

#pragma unroll
    for (int mi = 0; mi < 4; ++mi) {
#pragma unroll
        for (int reg = 0; reg < 4; ++reg) {
            int row = m0 + 16 * mi + 4 * q + reg;
            if (row < M) {
#pragma unroll
                for (int ni = 0; ni < 4; ++ni) {
                    int c = (w << 6) + (ni << 4) + c16;
                    float v = acc[mi][ni][reg];
                    C32[(size_t)row * DIM + c] = v;
                    C16[(size_t)row * DIM + c] = (_Float16)v;
                }
            }
        }
    }
}

// ---------------- fused edge GEMM: eft, ft_prime (f16), a, segment-max ----------------
__global__ __launch_bounds__(256) void k_gemm_edge(
    const float* __restrict__ efeat, const _Float16* __restrict__ WT,
    const float* __restrict__ ft32, const _Float16* __restrict__ ft16,
    const int* __restrict__ src, const int* __restrict__ dst,
    _Float16* __restrict__ ftp, float* __restrict__ a_ws, unsigned int* __restrict__ m_enc)
{
    __shared__ __align__(16) _Float16 Alds[64][296];
    const int t = threadIdx.x;
    const int e0 = blockIdx.x * 64;
    const int lane = t & 63, w = t >> 6;
    const int q = lane >> 4, c16 = lane & 15;
    const int srow = t >> 2;
    const int scol0 = (t & 3) * 64;
    const float* gp = efeat + (size_t)(e0 + srow) * DIM + scol0;
#pragma unroll
    for (int i = 0; i < 8; ++i) {
        float4 v0 = *(const float4*)(gp + i * 8);
        float4 v1 = *(const float4*)(gp + i * 8 + 4);
        f16x8 h8;
        h8[0]=(_Float16)v0.x; h8[1]=(_Float16)v0.y; h8[2]=(_Float16)v0.z; h8[3]=(_Float16)v0.w;
        h8[4]=(_Float16)v1.x; h8[5]=(_Float16)v1.y; h8[6]=(_Float16)v1.z; h8[7]=(_Float16)v1.w;
        *(f16x8*)&Alds[srow][scol0 + i * 8] = h8;
    }
    __syncthreads();

    f32x4v acc[4][4] = {};
#pragma unroll
    for (int k0 = 0; k0 < DIM; k0 += 32) {
        f16x8 bfr[4], afr[4];
#pragma unroll
        for (int ni = 0; ni < 4; ++ni) {
            int col = (w << 6) + (ni << 4) + c16;
            bfr[ni] = *(const f16x8*)(WT + (size_t)col * DIM + k0 + q * 8);
        }
#pragma unroll
        for (int mi = 0; mi < 4; ++mi)
            afr[mi] = *(const f16x8*)&Alds[c16 + 16 * mi][k0 + q * 8];
#pragma unroll
        for (int mi = 0; mi < 4; ++mi)
#pragma unroll
            for (int ni = 0; ni < 4; ++ni)
                acc[mi][ni] = __builtin_amdgcn_mfma_f32_16x16x32_f16(afr[mi], bfr[ni], acc[mi][ni], 0, 0, 0);
    }

    // write acc back to LDS (f16, A-layout) so the epilogue is row-major per thread
    __syncthreads();
#pragma unroll
    for (int mi = 0; mi < 4; ++mi)
#pragma unroll
        for (int reg = 0; reg < 4; ++reg) {
            int r = 16 * mi + 4 * q + reg;
#pragma unroll
            for (int ni = 0; ni < 4; ++ni) {
                int cc = (w << 6) + (ni << 4) + c16;
                Alds[r][cc] = (_Float16)acc[mi][ni][reg];
            }
        }
    __syncthreads();

    // row-major epilogue: thread t owns (edge e0 + (t>>2), head t&3)
    {
        int e = e0 + srow;
        int hh = t & 3;
        int se = src[e], de = dst[e];
        const _Float16* fs = ft16 + (size_t)se * DIM + scol0;
        const float*    fd = ft32 + (size_t)de * DIM + scol0;
        _Float16* fo = ftp + (size_t)e * DIM + scol0;
        float dotp = 0.f;
#pragma unroll
        for (int i = 0; i < 8; ++i) {
            f16x8 ev = *(const f16x8*)&Alds[srow][scol0 + i * 8];
            f16x8 s8 = *(const f16x8*)(fs + i * 8);
            float4 d0 = *(const float4*)(fd + i * 8);
            float4 d1 = *(const float4*)(fd + i * 8 + 4);
            float dv[8] = {d0.x, d0.y, d0.z, d0.w, d1.x, d1.y, d1.z, d1.w};
            f16x8 vp;
#pragma unroll
            for (int j = 0; j < 8; ++j) {
                float v = (float)ev[j] + (float)s8[j];
                vp[j] = (_Float16)v;
                dotp += v * dv[j];
            }
            *(f16x8*)(fo + i * 8) = vp;
        }
        a_ws[(size_t)e0 * H_HEADS + t] = dotp;   // == a_ws[e*4 + hh], coalesced
        unsigned int u = __float_as_uint(dotp);
        u = (u & 0x80000000u) ? ~u : (u | 0x80000000u);
        atomicMax(&m_enc[de * H_HEADS + hh], u);
    }
}

// ---------------- CSR aggregation with fused softmax (LDS-staged, parallel) ----------------
__device__ __forceinline__ float dec_max(unsigned int u)
{
    return (u & 0x80000000u) ? __uint_as_float(u & 0x7fffffffu) : __uint_as_float(~u);
}

__global__ __launch_bounds__(256) void k_agg(
    const unsigned int* __restrict__ offs, const int* __restrict__ esort,
    const float* __restrict__ a_ws, const unsigned int* __restrict__ m_enc,
    const _Float16* __restrict__ ftp, float* __restrict__ out)
{
    __shared__ int e_lds[AGG_CH];
    __shared__ float w_lds[AGG_CH * H_HEADS];
    __shared__ float s_part[4][4];
    __shared__ float s_tot[4];
    const int n = blockIdx.x, t = threadIdx.x;
    const int h = t >> 6;
    const int beg = (int)offs[n], end = (int)offs[n + 1];
    float mh[4];
#pragma unroll
    for (int k = 0; k < 4; ++k) mh[k] = dec_max(m_enc[n * H_HEADS + k]);

    // pass 1: softmax denominator (parallel over edge×head)
    float sp = 0.f;
    for (int base = beg; base < end; base += AGG_CH) {
        int cnt = min(AGG_CH, end - base);
        __syncthreads();
        if (t < cnt) e_lds[t] = esort[base + t];
        __syncthreads();
        for (int x = t; x < 4 * cnt; x += 256) {
            int j = x >> 2, k = x & 3;
            sp += __expf(a_ws[(size_t)e_lds[j] * H_HEADS + k] - mh[k]);
        }
    }
    sp += __shfl_xor(sp, 4);
    sp += __shfl_xor(sp, 8);
    sp += __shfl_xor(sp, 16);
    sp += __shfl_xor(sp, 32);
    if ((t & 63) < 4) s_part[t >> 6][t & 3] = sp;
    __syncthreads();
    if (t < 4) s_tot[t] = s_part[0][t] + s_part[1][t] + s_part[2][t] + s_part[3][t];
    __syncthreads();
    const float inv = (end > beg) ? 0.125f / s_tot[h] : 0.f;

    // pass 2: weighted aggregation
    float acc = 0.f;
    for (int base = beg; base < end; base += AGG_CH) {
        int cnt = min(AGG_CH, end - base);
        __syncthreads();
        if (t < cnt) e_lds[t] = esort[base + t];
        __syncthreads();
        for (int x = t; x < 4 * cnt; x += 256) {
            int j = x >> 2, k = x & 3;
            w_lds[j * 4 + k] = __expf(a_ws[(size_t)e_lds[j] * H_HEADS + k] - mh[k]);
        }
        __syncthreads();
        int j = 0;
        for (; j + 4 <= cnt; j += 4) {
            float p0 = (float)ftp[(size_t)e_lds[j    ] * DIM + t];
            float p1 = (float)ftp[(size_t)e_lds[j + 1] * DIM + t];
            float p2 = (float)ftp[(size_t)e_lds[j + 2] * DIM + t];
            float p3 = (float)ftp[(size_t)e_lds[j + 3] * DIM + t];
            acc += w_lds[j * 4 + h] * p0 + w_lds[(j + 1) * 4 + h] * p1
                 + w_lds[(j + 2) * 4 + h] * p2 + w_lds[(j + 3) * 4 + h] * p3;
        }
        for (; j < cnt; ++j)
            acc += w_lds[j * 4 + h] * (float)ftp[(size_t)e_lds[j] * DIM + t];
    }
    out[(size_t)n * DIM + t] = acc * inv;
}

// ---------------- launch ----------------
extern "C" void kernel_launch(void* const* d_in, const int* in_sizes, int n_in,
                              void* d_out, int out_size, void* d_ws, size_t ws_size,
                              hipStream_t stream)
{
    const float* nfeat = (const float*)d_in[0];
    const float* efeat = (const float*)d_in[1];
    const int* src = (const int*)d_in[2];
    const int* dst = (const int*)d_in[3];
    const float* Wn = (const float*)d_in[4];
    const float* We = (const float*)d_in[5];
    float* out = (float*)d_out;

    char* ws = (char*)d_ws;
    size_t off = 0;
    auto alloc = [&](size_t bytes) -> void* {
        off = (off + 255) & ~(size_t)255;
        void* p = ws + off;
        off += bytes;
        return p;
    };

    _Float16* WTn = (_Float16*)alloc((size_t)DIM * DIM * 2);
    _Float16* WTe = (_Float16*)alloc((size_t)DIM * DIM * 2);
    float* ft32 = (float*)alloc((size_t)N_NODES * DIM * 4);
    _Float16* ft16 = (_Float16*)alloc((size_t)N_NODES * DIM * 2);
    _Float16* ftp = (_Float16*)alloc((size_t)N_EDGES * DIM * 2);
    float* a_ws = (float*)alloc((size_t)N_EDGES * H_HEADS * 4);
    unsigned int* m_enc = (unsigned int*)alloc((size_t)N_NODES * H_HEADS * 4);
    unsigned int* counts = (unsigned int*)alloc((size_t)(N_NODES + 1) * 4);
    unsigned int* cursor = (unsigned int*)alloc((size_t)N_NODES * 4);
    int* esort = (int*)alloc((size_t)N_EDGES * 4);

    k_init<<<320, 256, 0, stream>>>(Wn, We, WTn, WTe, m_enc, counts);
    k_hist<<<(N_EDGES + 255) / 256, 256, 0, stream>>>(dst, counts);
    k_scan<<<1, 1024, 0, stream>>>(counts, cursor);
    k_scatter<<<(N_EDGES + 255) / 256, 256, 0, stream>>>(dst, cursor, esort);
    k_gemm_node<<<(N_NODES + 63) / 64, 256, 0, stream>>>(nfeat, WTn, ft32, ft16, N_NODES);
    k_gemm_edge<<<N_EDGES / 64, 256, 0, stream>>>(efeat, WTe, ft32, ft16, src, dst, ftp, a_ws, m_enc);
    k_agg<<<N_NODES, 256, 0, stream>>>(counts, esort, a_ws, m_enc, ftp, out);
}